// Round 12
// baseline (379.071 us; speedup 1.0000x reference)
//
#include <hip/hip_runtime.h>
#include <hip/hip_bf16.h>

#define DD 256
#define TROWS 32     // tile rows for node/edge/out kernels
#define BSTRIDE 264  // bf16 elements per row in LDS tiles (528 B, 16B-aligned)

typedef __attribute__((ext_vector_type(8))) short bf16x8;
typedef __attribute__((ext_vector_type(4))) float f32x4;

// v_cvt_pk_bf16_f32: D[15:0]=bf16(lo), D[31:16]=bf16(hi), RNE. No builtin on gfx950 (m240).
__device__ __forceinline__ unsigned cvt_pk_bf16(float lo, float hi) {
    unsigned r;
    asm("v_cvt_pk_bf16_f32 %0, %1, %2" : "=v"(r) : "v"(lo), "v"(hi));
    return r;
}

__device__ __forceinline__ ushort f2bf(float f) {   // scalar fallback (repack kernel)
    unsigned u = __float_as_uint(f);
    u += 0x7fffu + ((u >> 16) & 1u);
    return (ushort)(u >> 16);
}
__device__ __forceinline__ float bf2f(ushort h) {
    return __uint_as_float(((unsigned)h) << 16);
}

__device__ __forceinline__ float mish_f(float t) {
    float u = __expf(t);
    float w = u * (u + 2.0f);
    float r = t * w * __builtin_amdgcn_rcpf(w + 2.0f);
    return (t > 15.0f) ? t : r;
}

// Stage 32 rows x 256 cols fp32 -> bf16 LDS, XOR-swizzled (row*512 + (kbyte ^ ((row&7)<<4))).
__device__ __forceinline__ void stage32(const float* __restrict__ src, size_t rowStride,
                                        int rowsValid, char* lds) {
    const int t = threadIdx.x;
#pragma unroll
    for (int i = 0; i < 4; ++i) {
        int c = i * 256 + t;
        int row = c >> 5;
        int col8 = (c & 31) << 3;
        float4 va = make_float4(0.f, 0.f, 0.f, 0.f);
        float4 vb = va;
        if (row < rowsValid) {
            const float* p = src + (size_t)row * rowStride + col8;
            va = *(const float4*)p;
            vb = *(const float4*)(p + 4);
        }
        uint4 h;
        h.x = cvt_pk_bf16(va.x, va.y);
        h.y = cvt_pk_bf16(va.z, va.w);
        h.z = cvt_pk_bf16(vb.x, vb.y);
        h.w = cvt_pk_bf16(vb.z, vb.w);
        int off = row * 512 + ((((c & 31) << 4)) ^ ((row & 7) << 4));
        *(uint4*)(lds + off) = h;
    }
}

// GEMM core for a 32x256 tile: 4 waves; wave w covers rows [(w>>1)*16,+16) x cols [(w&1)*128,+128).
__device__ __forceinline__ void gemm32(const char* lds, const ushort* __restrict__ Wf,
                                       f32x4 acc[8]) {
    const int lane = threadIdx.x & 63;
    const int wave = threadIdx.x >> 6;
    const int arow = (wave >> 1) * 16 + (lane & 15);
    const int halfk = lane >> 4;
    const int ctg0 = (wave & 1) * 8;
    const bf16x8* Wfrag = (const bf16x8*)Wf;
#pragma unroll
    for (int ks = 0; ks < 8; ++ks) {
        int kbyte = ks * 64 + halfk * 16;
        bf16x8 a = *(const bf16x8*)(lds + arow * 512 + (kbyte ^ ((arow & 7) << 4)));
#pragma unroll
        for (int ct = 0; ct < 8; ++ct) {
            bf16x8 b = Wfrag[((ctg0 + ct) * 8 + ks) * 64 + lane];
            acc[ct] = __builtin_amdgcn_mfma_f32_16x16x32_bf16(a, b, acc[ct], 0, 0, 0);
        }
    }
}

// Repack W into fragment-major bf16.
__global__ void __launch_bounds__(256) convert_w_kernel(const float* __restrict__ in,
                                                        ushort* __restrict__ out, int nfrag) {
    int f = blockIdx.x * blockDim.x + threadIdx.x;
    if (f >= nfrag) return;
    int lane = f & 63;
    int ks = (f >> 6) & 7;
    int ct = f >> 9;
    int row = ct * 16 + (lane & 15);
    int kbase = ks * 32 + (lane >> 4) * 8;
    const float* p = in + (size_t)row * DD + kbase;
    float4 a = *(const float4*)p;
    float4 b = *(const float4*)(p + 4);
    ushort4 h0, h1;
    h0.x = f2bf(a.x); h0.y = f2bf(a.y); h0.z = f2bf(a.z); h0.w = f2bf(a.w);
    h1.x = f2bf(b.x); h1.y = f2bf(b.y); h1.z = f2bf(b.z); h1.w = f2bf(b.w);
    ushort4* o = (ushort4*)(out + (size_t)f * 8);
    o[0] = h0; o[1] = h1;
}

__global__ void __launch_bounds__(256) zero_kernel(int* __restrict__ p, int n) {
    int i = blockIdx.x * blockDim.x + threadIdx.x;
    if (i < n) p[i] = 0;
}

__global__ void __launch_bounds__(256) hist_kernel(const int* __restrict__ dst,
                                                   int* __restrict__ h, int E) {
    int e = blockIdx.x * blockDim.x + threadIdx.x;
    if (e < E) atomicAdd(&h[dst[e]], 1);
}

__global__ void __launch_bounds__(256) scan1_kernel(const int* __restrict__ h,
                                                    int* __restrict__ excl,
                                                    int* __restrict__ bsum, int n) {
    __shared__ int wsum[4];
    const int lane = threadIdx.x & 63;
    const int wave = threadIdx.x >> 6;
    int i = blockIdx.x * 256 + threadIdx.x;
    int v = (i < n) ? h[i] : 0;
    int s = v;
#pragma unroll
    for (int off = 1; off < 64; off <<= 1) {
        int u = __shfl_up(s, off, 64);
        if (lane >= off) s += u;
    }
    if (lane == 63) wsum[wave] = s;
    __syncthreads();
    int prefix = 0;
    for (int wv = 0; wv < wave; ++wv) prefix += wsum[wv];
    if (i < n) excl[i] = prefix + s - v;
    if (threadIdx.x == 255) bsum[blockIdx.x] = prefix + s;
}

__global__ void __launch_bounds__(256) scan2_kernel(int* __restrict__ bsum, int nb) {
    __shared__ int wsum[4];
    const int lane = threadIdx.x & 63;
    const int wave = threadIdx.x >> 6;
    int i = threadIdx.x;
    int v = (i < nb) ? bsum[i] : 0;
    int s = v;
#pragma unroll
    for (int off = 1; off < 64; off <<= 1) {
        int u = __shfl_up(s, off, 64);
        if (lane >= off) s += u;
    }
    if (lane == 63) wsum[wave] = s;
    __syncthreads();
    int prefix = 0;
    for (int wv = 0; wv < wave; ++wv) prefix += wsum[wv];
    if (i < nb) bsum[i] = prefix + s - v;
}

__global__ void __launch_bounds__(256) scan3_kernel(int* __restrict__ excl,
                                                    const int* __restrict__ bsum, int n) {
    int i = blockIdx.x * 256 + threadIdx.x;
    if (i < n) excl[i] += bsum[blockIdx.x];
}

__global__ void __launch_bounds__(256) scatter_kernel(const int* __restrict__ src,
                                                      const int* __restrict__ dst,
                                                      int* __restrict__ h2,
                                                      int* __restrict__ permS,
                                                      int* __restrict__ srcS,
                                                      int* __restrict__ dstS, int E) {
    int e = blockIdx.x * blockDim.x + threadIdx.x;
    if (e < E) {
        int d = dst[e];
        int pos = atomicAdd(&h2[d], 1);
        permS[pos] = e;
        srcS[pos] = src[e];
        dstS[pos] = d;
    }
}

// x = mish(node @ Wd^T + bd); write bf16 to xbf (ws) and f32 to agg (d_out)
__global__ void __launch_bounds__(256) node_kernel(const float* __restrict__ nf,
                                                   const ushort* __restrict__ Wd,
                                                   const float* __restrict__ bd,
                                                   ushort* __restrict__ xbf,
                                                   float* __restrict__ agg, int M) {
    __shared__ char lds[TROWS * 512];
    const int base = blockIdx.x * TROWS;
    const int rowsValid = min(TROWS, M - base);
    stage32(nf + (size_t)base * DD, DD, rowsValid, lds);
    __syncthreads();
    f32x4 acc[8];
#pragma unroll
    for (int i = 0; i < 8; ++i) acc[i] = (f32x4){0.f, 0.f, 0.f, 0.f};
    gemm32(lds, Wd, acc);
    const int lane = threadIdx.x & 63;
    const int wave = threadIdx.x >> 6;
    const int rowBase = (wave >> 1) * 16;
    const int colBase = (wave & 1) * 128;
    const int r = lane & 15, q = lane >> 4;
#pragma unroll
    for (int ct = 0; ct < 8; ++ct) {
        int col = colBase + ct * 16 + r;
        float bb = bd[col];
#pragma unroll
        for (int j = 0; j < 4; ++j) {
            int lrow = rowBase + q * 4 + j;
            if (lrow < rowsValid) {
                size_t idx = (size_t)(base + lrow) * DD + col;
                float m = mish_f(acc[ct][j] + bb);
                xbf[idx] = (ushort)cvt_pk_bf16(m, m);
                agg[idx] = m;
            }
        }
    }
}

// PASS A: y_sorted[i] = mish(ef[perm[i]] @ We^T + be), bf16, written coalesced.
// Streaming: stage -> GEMM -> LDS repack -> int4 stores. No gather/reduce here.
__global__ void __launch_bounds__(256, 5) edge_gemm_kernel(const float* __restrict__ ef,
                                                           const ushort* __restrict__ We,
                                                           const float* __restrict__ be,
                                                           const int* __restrict__ permS,
                                                           ushort* __restrict__ y, int E) {
    __shared__ char smem[TROWS * BSTRIDE * 2];
    __shared__ int permRow[TROWS];
    const int t = threadIdx.x;
    const int base = blockIdx.x * TROWS;
    const int rowsValid = min(TROWS, E - base);

    if (t < TROWS) {
        int gi = base + t;
        permRow[t] = permS[(gi < E) ? gi : (E - 1)];
    }
    __syncthreads();

    // Stage ef rows via perm (4 iters, cvt_pk, swizzled 16B ds_writes).
#pragma unroll
    for (int i = 0; i < 4; ++i) {
        int c = i * 256 + t;
        int row = c >> 5;
        int col8 = (c & 31) << 3;
        float4 va = make_float4(0.f, 0.f, 0.f, 0.f);
        float4 vb = va;
        if (row < rowsValid) {
            const float* p = ef + (size_t)permRow[row] * DD + col8;
            va = *(const float4*)p;
            vb = *(const float4*)(p + 4);
        }
        uint4 h;
        h.x = cvt_pk_bf16(va.x, va.y);
        h.y = cvt_pk_bf16(va.z, va.w);
        h.z = cvt_pk_bf16(vb.x, vb.y);
        h.w = cvt_pk_bf16(vb.z, vb.w);
        int off = row * 512 + ((((c & 31) << 4)) ^ ((row & 7) << 4));
        *(uint4*)(smem + off) = h;
    }
    __syncthreads();

    f32x4 acc[8];
#pragma unroll
    for (int i = 0; i < 8; ++i) acc[i] = (f32x4){0.f, 0.f, 0.f, 0.f};
    gemm32(smem, We, acc);
    __syncthreads();   // staged ef consumed

    // Repack y into LDS (unswizzled [32][BSTRIDE]) for coalesced stores.
    ushort* yt = (ushort*)smem;
    const int lane = t & 63;
    const int wave = t >> 6;
    const int rowBase = (wave >> 1) * 16;
    const int colBase = (wave & 1) * 128;
    const int r = lane & 15, q = lane >> 4;
#pragma unroll
    for (int ct = 0; ct < 8; ++ct) {
        int col = colBase + ct * 16 + r;
        float bb = be[col];
#pragma unroll
        for (int j = 0; j < 4; ++j) {
            int lrow = rowBase + q * 4 + j;
            float yv = mish_f(acc[ct][j] + bb);
            yt[lrow * BSTRIDE + col] = (ushort)cvt_pk_bf16(yv, yv);
        }
    }
    __syncthreads();

    // Coalesced stores: 4 iters of int4 (per wave: 2 rows x 512B segments).
#pragma unroll
    for (int i = 0; i < 4; ++i) {
        int c = i * 256 + t;
        int row = c >> 5;
        int col8 = (c & 31) << 3;
        if (row < rowsValid)
            *(int4*)(y + (size_t)(base + row) * DD + col8) = *(const int4*)(yt + row * BSTRIDE + col8);
    }
}

// PASS B: msg = relu(x[srcS[i]] + y_sorted[i]); run-reduce over sorted dst; atomicAdd.
// Thread t owns column t; barrier-free after index setup; all data via registers.
__global__ void __launch_bounds__(256) combine_kernel(const ushort* __restrict__ y,
                                                      const ushort* __restrict__ xbf,
                                                      const int* __restrict__ srcS,
                                                      const int* __restrict__ dstS,
                                                      float* __restrict__ agg, int E) {
    __shared__ int srcRow[TROWS];
    __shared__ int dstRow[TROWS];
    const int t = threadIdx.x;
    const int base = blockIdx.x * TROWS;

    if (t < TROWS) {
        int gi = base + t;
        srcRow[t] = srcS[(gi < E) ? gi : (E - 1)];
        dstRow[t] = (gi < E) ? dstS[gi] : -1;
    }
    __syncthreads();

    const int col = t;
    float run = 0.f;
    int dprev = dstRow[0];
#pragma unroll
    for (int c0 = 0; c0 < TROWS; c0 += 8) {
        ushort yv[8], xv[8];
#pragma unroll
        for (int j = 0; j < 8; ++j) {
            int gi = base + c0 + j;
            int gic = (gi < E) ? gi : (E - 1);
            yv[j] = y[(size_t)gic * DD + col];
            xv[j] = xbf[(size_t)srcRow[c0 + j] * DD + col];
        }
#pragma unroll
        for (int j = 0; j < 8; ++j) {
            int d = dstRow[c0 + j];
            if (d != dprev) {
                if (dprev >= 0) atomicAdd(agg + (size_t)dprev * DD + col, run);
                run = 0.f;
                dprev = d;
            }
            if (d >= 0) run += fmaxf(bf2f(xv[j]) + bf2f(yv[j]), 0.f);
        }
    }
    if (dprev >= 0) atomicAdd(agg + (size_t)dprev * DD + col, run);
}

// out = mish(agg @ Wo^T + bo), in place on agg (= d_out)
__global__ void __launch_bounds__(256) out_kernel(const ushort* __restrict__ Wo,
                                                  const float* __restrict__ bo,
                                                  float* __restrict__ agg_out, int M) {
    __shared__ char lds[TROWS * 512];
    const int base = blockIdx.x * TROWS;
    const int rowsValid = min(TROWS, M - base);
    stage32(agg_out + (size_t)base * DD, DD, rowsValid, lds);
    __syncthreads();
    f32x4 acc[8];
#pragma unroll
    for (int i = 0; i < 8; ++i) acc[i] = (f32x4){0.f, 0.f, 0.f, 0.f};
    gemm32(lds, Wo, acc);
    const int lane = threadIdx.x & 63;
    const int wave = threadIdx.x >> 6;
    const int rowBase = (wave >> 1) * 16;
    const int colBase = (wave & 1) * 128;
    const int r = lane & 15, q = lane >> 4;
#pragma unroll
    for (int ct = 0; ct < 8; ++ct) {
        int col = colBase + ct * 16 + r;
        float bb = bo[col];
#pragma unroll
        for (int j = 0; j < 4; ++j) {
            int lrow = rowBase + q * 4 + j;
            if (lrow < rowsValid) {
                size_t idx = (size_t)(base + lrow) * DD + col;
                agg_out[idx] = mish_f(acc[ct][j] + bb);
            }
        }
    }
}

extern "C" void kernel_launch(void* const* d_in, const int* in_sizes, int n_in,
                              void* d_out, int out_size, void* d_ws, size_t ws_size,
                              hipStream_t stream) {
    const float* nf = (const float*)d_in[0];
    const float* ef = (const float*)d_in[1];
    const int* src = (const int*)d_in[3];
    const int* dst = (const int*)d_in[4];
    const float* Wd = (const float*)d_in[5];
    const float* bd = (const float*)d_in[6];
    const float* We = (const float*)d_in[7];
    const float* be = (const float*)d_in[8];
    const float* Wo = (const float*)d_in[9];
    const float* bo = (const float*)d_in[10];

    const int M = in_sizes[0] / DD;   // 20000
    const int E = in_sizes[1] / DD;   // 320000
    float* out = (float*)d_out;       // agg: rst = x + sum(msg)

    auto align = [](size_t v) { return (v + 255) & ~(size_t)255; };
    char* ws = (char*)d_ws;
    size_t off = 0;
    ushort* xbf = (ushort*)(ws + off); off += align((size_t)M * DD * 2);
    ushort* Wdb = (ushort*)(ws + off); off += align((size_t)DD * DD * 2);
    ushort* Web = (ushort*)(ws + off); off += align((size_t)DD * DD * 2);
    ushort* Wob = (ushort*)(ws + off); off += align((size_t)DD * DD * 2);
    int* h     = (int*)(ws + off); off += align((size_t)M * 4);
    int* h2    = (int*)(ws + off); off += align((size_t)M * 4);
    int* bsum  = (int*)(ws + off); off += align(256 * 4);
    int* permS = (int*)(ws + off); off += align((size_t)E * 4);
    int* srcS  = (int*)(ws + off); off += align((size_t)E * 4);
    int* dstS  = (int*)(ws + off); off += align((size_t)E * 4);
    // y buffer: remaining ws, chunked if it can't hold all E rows (164 MB).
    ushort* yws = (ushort*)(ws + off);
    size_t yspace = (ws_size > off) ? (ws_size - off) : 0;
    long ycapRows = (long)(yspace / ((size_t)DD * 2));
    int chunkE = (int)((ycapRows / TROWS) * TROWS);
    if (chunkE < TROWS) chunkE = TROWS;           // assume ws provides at least one tile
    if (chunkE > E) chunkE = E;

    const int nfrag = (DD / 16) * (DD / 32) * 64;
    convert_w_kernel<<<(nfrag + 255) / 256, 256, 0, stream>>>(Wd, Wdb, nfrag);
    convert_w_kernel<<<(nfrag + 255) / 256, 256, 0, stream>>>(We, Web, nfrag);
    convert_w_kernel<<<(nfrag + 255) / 256, 256, 0, stream>>>(Wo, Wob, nfrag);

    // Counting sort by dst (hierarchical scan)
    const int nbScan = (M + 255) / 256;
    zero_kernel<<<(M + 255) / 256, 256, 0, stream>>>(h, M);
    hist_kernel<<<(E + 255) / 256, 256, 0, stream>>>(dst, h, E);
    scan1_kernel<<<nbScan, 256, 0, stream>>>(h, h2, bsum, M);
    scan2_kernel<<<1, 256, 0, stream>>>(bsum, nbScan);
    scan3_kernel<<<nbScan, 256, 0, stream>>>(h2, bsum, M);
    scatter_kernel<<<(E + 255) / 256, 256, 0, stream>>>(src, dst, h2, permS, srcS, dstS, E);

    const int nwgN = (M + TROWS - 1) / TROWS;
    node_kernel<<<nwgN, 256, 0, stream>>>(nf, Wdb, bd, xbf, out, M);

    for (int e0 = 0; e0 < E; e0 += chunkE) {
        int ecnt = min(chunkE, E - e0);
        int nwg = (ecnt + TROWS - 1) / TROWS;
        edge_gemm_kernel<<<nwg, 256, 0, stream>>>(ef, Web, be, permS + e0, yws, ecnt);
        combine_kernel<<<nwg, 256, 0, stream>>>(yws, xbf, srcS + e0, dstS + e0, out, ecnt);
    }

    out_kernel<<<nwgN, 256, 0, stream>>>(Wob, bo, out, M);
}

// Round 13
// 278.049 us; speedup vs baseline: 1.3633x; 1.3633x over previous
//
#include <hip/hip_runtime.h>
#include <hip/hip_bf16.h>

#define DD 256
#define TROWS 16     // tile rows (r13: halved again -> acc[4], ~40 VGPR, 8 blocks/CU)
#define BSTRIDE 264  // bf16 elements per row in LDS tiles (528 B, 16B-aligned)

typedef __attribute__((ext_vector_type(8))) short bf16x8;
typedef __attribute__((ext_vector_type(4))) float f32x4;

// v_cvt_pk_bf16_f32: D[15:0]=bf16(lo), D[31:16]=bf16(hi), RNE. No builtin on gfx950 (m240).
__device__ __forceinline__ unsigned cvt_pk_bf16(float lo, float hi) {
    unsigned r;
    asm("v_cvt_pk_bf16_f32 %0, %1, %2" : "=v"(r) : "v"(lo), "v"(hi));
    return r;
}

__device__ __forceinline__ ushort f2bf(float f) {   // scalar fallback (repack kernel)
    unsigned u = __float_as_uint(f);
    u += 0x7fffu + ((u >> 16) & 1u);
    return (ushort)(u >> 16);
}
__device__ __forceinline__ float bf2f(ushort h) {
    return __uint_as_float(((unsigned)h) << 16);
}

__device__ __forceinline__ float mish_f(float t) {
    float u = __expf(t);
    float w = u * (u + 2.0f);
    float r = t * w * __builtin_amdgcn_rcpf(w + 2.0f);
    return (t > 15.0f) ? t : r;
}

// Stage 16 rows x 256 cols fp32 -> bf16 LDS, XOR-swizzled (row*512 + (kbyte ^ ((row&7)<<4))).
// 2 iterations; each thread converts 8 floats via 4 cvt_pk -> one 16B ds_write.
__device__ __forceinline__ void stage16(const float* __restrict__ src, size_t rowStride,
                                        int rowsValid, char* lds) {
    const int t = threadIdx.x;
#pragma unroll
    for (int i = 0; i < 2; ++i) {
        int c = i * 256 + t;           // 16B-dest chunk id, 0..511
        int row = c >> 5;              // 32 chunks per row
        int col8 = (c & 31) << 3;      // 8-float group
        float4 va = make_float4(0.f, 0.f, 0.f, 0.f);
        float4 vb = va;
        if (row < rowsValid) {
            const float* p = src + (size_t)row * rowStride + col8;
            va = *(const float4*)p;
            vb = *(const float4*)(p + 4);
        }
        uint4 h;
        h.x = cvt_pk_bf16(va.x, va.y);
        h.y = cvt_pk_bf16(va.z, va.w);
        h.z = cvt_pk_bf16(vb.x, vb.y);
        h.w = cvt_pk_bf16(vb.z, vb.w);
        int off = row * 512 + ((((c & 31) << 4)) ^ ((row & 7) << 4));
        *(uint4*)(lds + off) = h;
    }
}

// GEMM core for a 16x256 tile: 4 waves; wave w covers rows 0-15 x cols [w*64, +64).
// B fragment-major: Wf[(ct*8+ks)*64+lane] = contiguous 1KB wave-load.
__device__ __forceinline__ void gemm16(const char* lds, const ushort* __restrict__ Wf,
                                       f32x4 acc[4]) {
    const int lane = threadIdx.x & 63;
    const int wave = threadIdx.x >> 6;
    const int arow = lane & 15;
    const int halfk = lane >> 4;
    const int ctg0 = wave * 4;
    const bf16x8* Wfrag = (const bf16x8*)Wf;
#pragma unroll
    for (int ks = 0; ks < 8; ++ks) {
        int kbyte = ks * 64 + halfk * 16;
        bf16x8 a = *(const bf16x8*)(lds + arow * 512 + (kbyte ^ ((arow & 7) << 4)));
#pragma unroll
        for (int ct = 0; ct < 4; ++ct) {
            bf16x8 b = Wfrag[((ctg0 + ct) * 8 + ks) * 64 + lane];
            acc[ct] = __builtin_amdgcn_mfma_f32_16x16x32_bf16(a, b, acc[ct], 0, 0, 0);
        }
    }
}

// Repack W into fragment-major bf16.
__global__ void __launch_bounds__(256) convert_w_kernel(const float* __restrict__ in,
                                                        ushort* __restrict__ out, int nfrag) {
    int f = blockIdx.x * blockDim.x + threadIdx.x;
    if (f >= nfrag) return;
    int lane = f & 63;
    int ks = (f >> 6) & 7;
    int ct = f >> 9;
    int row = ct * 16 + (lane & 15);
    int kbase = ks * 32 + (lane >> 4) * 8;
    const float* p = in + (size_t)row * DD + kbase;
    float4 a = *(const float4*)p;
    float4 b = *(const float4*)(p + 4);
    ushort4 h0, h1;
    h0.x = f2bf(a.x); h0.y = f2bf(a.y); h0.z = f2bf(a.z); h0.w = f2bf(a.w);
    h1.x = f2bf(b.x); h1.y = f2bf(b.y); h1.z = f2bf(b.z); h1.w = f2bf(b.w);
    ushort4* o = (ushort4*)(out + (size_t)f * 8);
    o[0] = h0; o[1] = h1;
}

__global__ void __launch_bounds__(256) zero_kernel(int* __restrict__ p, int n) {
    int i = blockIdx.x * blockDim.x + threadIdx.x;
    if (i < n) p[i] = 0;
}

__global__ void __launch_bounds__(256) hist_kernel(const int* __restrict__ dst,
                                                   int* __restrict__ h, int E) {
    int e = blockIdx.x * blockDim.x + threadIdx.x;
    if (e < E) atomicAdd(&h[dst[e]], 1);
}

__global__ void __launch_bounds__(256) scan1_kernel(const int* __restrict__ h,
                                                    int* __restrict__ excl,
                                                    int* __restrict__ bsum, int n) {
    __shared__ int wsum[4];
    const int lane = threadIdx.x & 63;
    const int wave = threadIdx.x >> 6;
    int i = blockIdx.x * 256 + threadIdx.x;
    int v = (i < n) ? h[i] : 0;
    int s = v;
#pragma unroll
    for (int off = 1; off < 64; off <<= 1) {
        int u = __shfl_up(s, off, 64);
        if (lane >= off) s += u;
    }
    if (lane == 63) wsum[wave] = s;
    __syncthreads();
    int prefix = 0;
    for (int wv = 0; wv < wave; ++wv) prefix += wsum[wv];
    if (i < n) excl[i] = prefix + s - v;
    if (threadIdx.x == 255) bsum[blockIdx.x] = prefix + s;
}

__global__ void __launch_bounds__(256) scan2_kernel(int* __restrict__ bsum, int nb) {
    __shared__ int wsum[4];
    const int lane = threadIdx.x & 63;
    const int wave = threadIdx.x >> 6;
    int i = threadIdx.x;
    int v = (i < nb) ? bsum[i] : 0;
    int s = v;
#pragma unroll
    for (int off = 1; off < 64; off <<= 1) {
        int u = __shfl_up(s, off, 64);
        if (lane >= off) s += u;
    }
    if (lane == 63) wsum[wave] = s;
    __syncthreads();
    int prefix = 0;
    for (int wv = 0; wv < wave; ++wv) prefix += wsum[wv];
    if (i < nb) bsum[i] = prefix + s - v;
}

__global__ void __launch_bounds__(256) scan3_kernel(int* __restrict__ excl,
                                                    const int* __restrict__ bsum, int n) {
    int i = blockIdx.x * 256 + threadIdx.x;
    if (i < n) excl[i] += bsum[blockIdx.x];
}

__global__ void __launch_bounds__(256) scatter_kernel(const int* __restrict__ src,
                                                      const int* __restrict__ dst,
                                                      int* __restrict__ h2,
                                                      int* __restrict__ permS,
                                                      int* __restrict__ srcS,
                                                      int* __restrict__ dstS, int E) {
    int e = blockIdx.x * blockDim.x + threadIdx.x;
    if (e < E) {
        int d = dst[e];
        int pos = atomicAdd(&h2[d], 1);
        permS[pos] = e;
        srcS[pos] = src[e];
        dstS[pos] = d;
    }
}

// x = mish(node @ Wd^T + bd); write bf16 to xbf (ws) and f32 to agg (d_out)
__global__ void __launch_bounds__(256, 8) node_kernel(const float* __restrict__ nf,
                                                      const ushort* __restrict__ Wd,
                                                      const float* __restrict__ bd,
                                                      ushort* __restrict__ xbf,
                                                      float* __restrict__ agg, int M) {
    __shared__ char lds[TROWS * 512];
    const int base = blockIdx.x * TROWS;
    const int rowsValid = min(TROWS, M - base);
    stage16(nf + (size_t)base * DD, DD, rowsValid, lds);
    __syncthreads();
    f32x4 acc[4];
#pragma unroll
    for (int i = 0; i < 4; ++i) acc[i] = (f32x4){0.f, 0.f, 0.f, 0.f};
    gemm16(lds, Wd, acc);
    const int lane = threadIdx.x & 63;
    const int wave = threadIdx.x >> 6;
    const int colBase = wave * 64;
    const int r = lane & 15, q = lane >> 4;
#pragma unroll
    for (int ct = 0; ct < 4; ++ct) {
        int col = colBase + ct * 16 + r;
        float bb = bd[col];
#pragma unroll
        for (int j = 0; j < 4; ++j) {
            int lrow = q * 4 + j;
            if (lrow < rowsValid) {
                size_t idx = (size_t)(base + lrow) * DD + col;
                float m = mish_f(acc[ct][j] + bb);
                xbf[idx] = (ushort)cvt_pk_bf16(m, m);
                agg[idx] = m;
            }
        }
    }
}

// Sorted-edge kernel, 16-row tile: gather ef via perm, GEMM (4 waves x 16r x 64c),
// msg = relu(x[src]+y) into LDS, 16-iter run-reduce, atomicAdd per (run,col).
// acc[4]=16 regs -> total ~40 VGPR; (256,8) budget 64 -> 8 blocks/CU spill-free.
__global__ void __launch_bounds__(256, 8) edge_kernel(const float* __restrict__ ef,
                                                      const ushort* __restrict__ We,
                                                      const float* __restrict__ be,
                                                      const ushort* __restrict__ xbf,
                                                      const int* __restrict__ permS,
                                                      const int* __restrict__ srcS,
                                                      const int* __restrict__ dstS,
                                                      float* __restrict__ agg, int E) {
    __shared__ char smem[TROWS * BSTRIDE * 2];  // 8448 B: staging (16*512 swz) / xt (16*528)
    __shared__ int permRow[TROWS];
    __shared__ int srcRow[TROWS];
    __shared__ int dstRow[TROWS];

    const int t = threadIdx.x;
    const int base = blockIdx.x * TROWS;
    const int rowsValid = min(TROWS, E - base);

    if (t < TROWS) {
        int gi = base + t;
        int gic = (gi < E) ? gi : (E - 1);
        permRow[t] = permS[gic];
        srcRow[t] = srcS[gic];
        dstRow[t] = (gi < E) ? dstS[gic] : -1;
    }
    __syncthreads();

    // Stage ef rows (16 x 256 fp32 -> bf16 swizzled): 2 iters, cvt_pk + 16B ds_writes.
#pragma unroll
    for (int i = 0; i < 2; ++i) {
        int c = i * 256 + t;
        int row = c >> 5;
        int col8 = (c & 31) << 3;
        float4 va = make_float4(0.f, 0.f, 0.f, 0.f);
        float4 vb = va;
        if (row < rowsValid) {
            const float* p = ef + (size_t)permRow[row] * DD + col8;
            va = *(const float4*)p;
            vb = *(const float4*)(p + 4);
        }
        uint4 h;
        h.x = cvt_pk_bf16(va.x, va.y);
        h.y = cvt_pk_bf16(va.z, va.w);
        h.z = cvt_pk_bf16(vb.x, vb.y);
        h.w = cvt_pk_bf16(vb.z, vb.w);
        int off = row * 512 + ((((c & 31) << 4)) ^ ((row & 7) << 4));
        *(uint4*)(smem + off) = h;
    }
    __syncthreads();

    f32x4 acc[4];
#pragma unroll
    for (int i = 0; i < 4; ++i) acc[i] = (f32x4){0.f, 0.f, 0.f, 0.f};
    gemm16(smem, We, acc);
    __syncthreads();   // staged ef consumed; smem reusable

    // Stage x rows (16 x 256 bf16): 2 iters of int4.
    ushort* xt = (ushort*)smem;   // [16][BSTRIDE]
#pragma unroll
    for (int i = 0; i < 2; ++i) {
        int c = i * 256 + t;
        int row = c >> 5;
        int col8 = (c & 31) << 3;
        int4 v = make_int4(0, 0, 0, 0);
        if (row < rowsValid)
            v = *(const int4*)(xbf + (size_t)srcRow[row] * DD + col8);
        *(int4*)(xt + row * BSTRIDE + col8) = v;
    }
    __syncthreads();

    // Epilogue: y = mish(acc + be); msg = relu(x + y) written in place over xt.
    const int lane = t & 63;
    const int wave = t >> 6;
    const int colBase = wave * 64;
    const int r = lane & 15, q = lane >> 4;
#pragma unroll
    for (int ct = 0; ct < 4; ++ct) {
        int col = colBase + ct * 16 + r;
        float bb = be[col];
#pragma unroll
        for (int j = 0; j < 4; ++j) {
            int lrow = q * 4 + j;
            float y = mish_f(acc[ct][j] + bb);
            float xval = bf2f(xt[lrow * BSTRIDE + col]);
            float msg = (lrow < rowsValid) ? fmaxf(xval + y, 0.f) : 0.f;
            xt[lrow * BSTRIDE + col] = (ushort)cvt_pk_bf16(msg, msg);
        }
    }
    __syncthreads();

    // Run-reduction: thread t owns col t; dst broadcast -> uniform branches.
    {
        int col = t;
        float run = 0.f;
        int dprev = dstRow[0];
#pragma unroll
        for (int r2 = 0; r2 < TROWS; ++r2) {
            int d = dstRow[r2];
            if (d != dprev) {
                if (dprev >= 0) atomicAdd(agg + (size_t)dprev * DD + col, run);
                run = 0.f;
                dprev = d;
            }
            run += bf2f(xt[r2 * BSTRIDE + col]);
        }
        if (dprev >= 0) atomicAdd(agg + (size_t)dprev * DD + col, run);
    }
}

// out = mish(agg @ Wo^T + bo), in place on agg (= d_out)
__global__ void __launch_bounds__(256, 8) out_kernel(const ushort* __restrict__ Wo,
                                                     const float* __restrict__ bo,
                                                     float* __restrict__ agg_out, int M) {
    __shared__ char lds[TROWS * 512];
    const int base = blockIdx.x * TROWS;
    const int rowsValid = min(TROWS, M - base);
    stage16(agg_out + (size_t)base * DD, DD, rowsValid, lds);
    __syncthreads();
    f32x4 acc[4];
#pragma unroll
    for (int i = 0; i < 4; ++i) acc[i] = (f32x4){0.f, 0.f, 0.f, 0.f};
    gemm16(lds, Wo, acc);
    const int lane = threadIdx.x & 63;
    const int wave = threadIdx.x >> 6;
    const int colBase = wave * 64;
    const int r = lane & 15, q = lane >> 4;
#pragma unroll
    for (int ct = 0; ct < 4; ++ct) {
        int col = colBase + ct * 16 + r;
        float bb = bo[col];
#pragma unroll
        for (int j = 0; j < 4; ++j) {
            int lrow = q * 4 + j;
            if (lrow < rowsValid) {
                size_t idx = (size_t)(base + lrow) * DD + col;
                agg_out[idx] = mish_f(acc[ct][j] + bb);
            }
        }
    }
}

extern "C" void kernel_launch(void* const* d_in, const int* in_sizes, int n_in,
                              void* d_out, int out_size, void* d_ws, size_t ws_size,
                              hipStream_t stream) {
    const float* nf = (const float*)d_in[0];
    const float* ef = (const float*)d_in[1];
    const int* src = (const int*)d_in[3];
    const int* dst = (const int*)d_in[4];
    const float* Wd = (const float*)d_in[5];
    const float* bd = (const float*)d_in[6];
    const float* We = (const float*)d_in[7];
    const float* be = (const float*)d_in[8];
    const float* Wo = (const float*)d_in[9];
    const float* bo = (const float*)d_in[10];

    const int M = in_sizes[0] / DD;   // 20000
    const int E = in_sizes[1] / DD;   // 320000
    float* out = (float*)d_out;       // agg: rst = x + sum(msg)

    auto align = [](size_t v) { return (v + 255) & ~(size_t)255; };
    char* ws = (char*)d_ws;
    size_t off = 0;
    ushort* xbf = (ushort*)(ws + off); off += align((size_t)M * DD * 2);
    ushort* Wdb = (ushort*)(ws + off); off += align((size_t)DD * DD * 2);
    ushort* Web = (ushort*)(ws + off); off += align((size_t)DD * DD * 2);
    ushort* Wob = (ushort*)(ws + off); off += align((size_t)DD * DD * 2);
    int* h     = (int*)(ws + off); off += align((size_t)M * 4);
    int* h2    = (int*)(ws + off); off += align((size_t)M * 4);
    int* bsum  = (int*)(ws + off); off += align(256 * 4);
    int* permS = (int*)(ws + off); off += align((size_t)E * 4);
    int* srcS  = (int*)(ws + off); off += align((size_t)E * 4);
    int* dstS  = (int*)(ws + off); off += align((size_t)E * 4);

    const int nfrag = (DD / 16) * (DD / 32) * 64;  // 8192 fragments per weight
    convert_w_kernel<<<(nfrag + 255) / 256, 256, 0, stream>>>(Wd, Wdb, nfrag);
    convert_w_kernel<<<(nfrag + 255) / 256, 256, 0, stream>>>(We, Web, nfrag);
    convert_w_kernel<<<(nfrag + 255) / 256, 256, 0, stream>>>(Wo, Wob, nfrag);

    // Counting sort by dst (hierarchical scan)
    const int nbScan = (M + 255) / 256;
    zero_kernel<<<(M + 255) / 256, 256, 0, stream>>>(h, M);
    hist_kernel<<<(E + 255) / 256, 256, 0, stream>>>(dst, h, E);
    scan1_kernel<<<nbScan, 256, 0, stream>>>(h, h2, bsum, M);
    scan2_kernel<<<1, 256, 0, stream>>>(bsum, nbScan);
    scan3_kernel<<<nbScan, 256, 0, stream>>>(h2, bsum, M);
    scatter_kernel<<<(E + 255) / 256, 256, 0, stream>>>(src, dst, h2, permS, srcS, dstS, E);

    const int nwgN = (M + TROWS - 1) / TROWS;   // 1250
    node_kernel<<<nwgN, 256, 0, stream>>>(nf, Wdb, bd, xbf, out, M);
    const int nwgE = (E + TROWS - 1) / TROWS;   // 20000
    edge_kernel<<<nwgE, 256, 0, stream>>>(ef, Web, be, xbf, permS, srcS, dstS, out, E);
    out_kernel<<<nwgN, 256, 0, stream>>>(Wob, bo, out, M);
}

// Round 14
// 271.678 us; speedup vs baseline: 1.3953x; 1.0235x over previous
//
#include <hip/hip_runtime.h>
#include <hip/hip_bf16.h>

#define DD 256
#define TROWS 16     // tile rows; acc[4] -> ~40 VGPR, 8 blocks/CU (HW wave cap)
#define BSTRIDE 264  // bf16 elements per row in LDS tiles (528 B, 16B-aligned)

typedef __attribute__((ext_vector_type(8))) short bf16x8;
typedef __attribute__((ext_vector_type(4))) float f32x4;

// v_cvt_pk_bf16_f32: D[15:0]=bf16(lo), D[31:16]=bf16(hi), RNE. No builtin on gfx950 (m240).
__device__ __forceinline__ unsigned cvt_pk_bf16(float lo, float hi) {
    unsigned r;
    asm("v_cvt_pk_bf16_f32 %0, %1, %2" : "=v"(r) : "v"(lo), "v"(hi));
    return r;
}

__device__ __forceinline__ ushort f2bf(float f) {   // scalar fallback (repack kernel)
    unsigned u = __float_as_uint(f);
    u += 0x7fffu + ((u >> 16) & 1u);
    return (ushort)(u >> 16);
}
__device__ __forceinline__ float bf2f(ushort h) {
    return __uint_as_float(((unsigned)h) << 16);
}

__device__ __forceinline__ float mish_f(float t) {
    float u = __expf(t);
    float w = u * (u + 2.0f);
    float r = t * w * __builtin_amdgcn_rcpf(w + 2.0f);
    return (t > 15.0f) ? t : r;
}

// Stage 16 rows x 256 cols fp32 -> bf16 LDS, XOR-swizzled (row*512 + (kbyte ^ ((row&7)<<4))).
__device__ __forceinline__ void stage16(const float* __restrict__ src, size_t rowStride,
                                        int rowsValid, char* lds) {
    const int t = threadIdx.x;
#pragma unroll
    for (int i = 0; i < 2; ++i) {
        int c = i * 256 + t;           // 16B-dest chunk id, 0..511
        int row = c >> 5;              // 32 chunks per row
        int col8 = (c & 31) << 3;      // 8-float group
        float4 va = make_float4(0.f, 0.f, 0.f, 0.f);
        float4 vb = va;
        if (row < rowsValid) {
            const float* p = src + (size_t)row * rowStride + col8;
            va = *(const float4*)p;
            vb = *(const float4*)(p + 4);
        }
        uint4 h;
        h.x = cvt_pk_bf16(va.x, va.y);
        h.y = cvt_pk_bf16(va.z, va.w);
        h.z = cvt_pk_bf16(vb.x, vb.y);
        h.w = cvt_pk_bf16(vb.z, vb.w);
        int off = row * 512 + ((((c & 31) << 4)) ^ ((row & 7) << 4));
        *(uint4*)(lds + off) = h;
    }
}

// GEMM core for a 16x256 tile: 4 waves; wave w covers rows 0-15 x cols [w*64, +64).
__device__ __forceinline__ void gemm16(const char* lds, const ushort* __restrict__ Wf,
                                       f32x4 acc[4]) {
    const int lane = threadIdx.x & 63;
    const int wave = threadIdx.x >> 6;
    const int arow = lane & 15;
    const int halfk = lane >> 4;
    const int ctg0 = wave * 4;
    const bf16x8* Wfrag = (const bf16x8*)Wf;
#pragma unroll
    for (int ks = 0; ks < 8; ++ks) {
        int kbyte = ks * 64 + halfk * 16;
        bf16x8 a = *(const bf16x8*)(lds + arow * 512 + (kbyte ^ ((arow & 7) << 4)));
#pragma unroll
        for (int ct = 0; ct < 4; ++ct) {
            bf16x8 b = Wfrag[((ctg0 + ct) * 8 + ks) * 64 + lane];
            acc[ct] = __builtin_amdgcn_mfma_f32_16x16x32_bf16(a, b, acc[ct], 0, 0, 0);
        }
    }
}

// Repack W into fragment-major bf16.
__global__ void __launch_bounds__(256) convert_w_kernel(const float* __restrict__ in,
                                                        ushort* __restrict__ out, int nfrag) {
    int f = blockIdx.x * blockDim.x + threadIdx.x;
    if (f >= nfrag) return;
    int lane = f & 63;
    int ks = (f >> 6) & 7;
    int ct = f >> 9;
    int row = ct * 16 + (lane & 15);
    int kbase = ks * 32 + (lane >> 4) * 8;
    const float* p = in + (size_t)row * DD + kbase;
    float4 a = *(const float4*)p;
    float4 b = *(const float4*)(p + 4);
    ushort4 h0, h1;
    h0.x = f2bf(a.x); h0.y = f2bf(a.y); h0.z = f2bf(a.z); h0.w = f2bf(a.w);
    h1.x = f2bf(b.x); h1.y = f2bf(b.y); h1.z = f2bf(b.z); h1.w = f2bf(b.w);
    ushort4* o = (ushort4*)(out + (size_t)f * 8);
    o[0] = h0; o[1] = h1;
}

__global__ void __launch_bounds__(256) zero_kernel(int* __restrict__ p, int n) {
    int i = blockIdx.x * blockDim.x + threadIdx.x;
    if (i < n) p[i] = 0;
}

__global__ void __launch_bounds__(256) hist_kernel(const int* __restrict__ dst,
                                                   int* __restrict__ h, int E) {
    int e = blockIdx.x * blockDim.x + threadIdx.x;
    if (e < E) atomicAdd(&h[dst[e]], 1);
}

__global__ void __launch_bounds__(256) scan1_kernel(const int* __restrict__ h,
                                                    int* __restrict__ excl,
                                                    int* __restrict__ bsum, int n) {
    __shared__ int wsum[4];
    const int lane = threadIdx.x & 63;
    const int wave = threadIdx.x >> 6;
    int i = blockIdx.x * 256 + threadIdx.x;
    int v = (i < n) ? h[i] : 0;
    int s = v;
#pragma unroll
    for (int off = 1; off < 64; off <<= 1) {
        int u = __shfl_up(s, off, 64);
        if (lane >= off) s += u;
    }
    if (lane == 63) wsum[wave] = s;
    __syncthreads();
    int prefix = 0;
    for (int wv = 0; wv < wave; ++wv) prefix += wsum[wv];
    if (i < n) excl[i] = prefix + s - v;
    if (threadIdx.x == 255) bsum[blockIdx.x] = prefix + s;
}

__global__ void __launch_bounds__(256) scan2_kernel(int* __restrict__ bsum, int nb) {
    __shared__ int wsum[4];
    const int lane = threadIdx.x & 63;
    const int wave = threadIdx.x >> 6;
    int i = threadIdx.x;
    int v = (i < nb) ? bsum[i] : 0;
    int s = v;
#pragma unroll
    for (int off = 1; off < 64; off <<= 1) {
        int u = __shfl_up(s, off, 64);
        if (lane >= off) s += u;
    }
    if (lane == 63) wsum[wave] = s;
    __syncthreads();
    int prefix = 0;
    for (int wv = 0; wv < wave; ++wv) prefix += wsum[wv];
    if (i < nb) bsum[i] = prefix + s - v;
}

__global__ void __launch_bounds__(256) scan3_kernel(int* __restrict__ excl,
                                                    const int* __restrict__ bsum, int n) {
    int i = blockIdx.x * 256 + threadIdx.x;
    if (i < n) excl[i] += bsum[blockIdx.x];
}

__global__ void __launch_bounds__(256) scatter_kernel(const int* __restrict__ src,
                                                      const int* __restrict__ dst,
                                                      int* __restrict__ h2,
                                                      int* __restrict__ permS,
                                                      int* __restrict__ srcS,
                                                      int* __restrict__ dstS, int E) {
    int e = blockIdx.x * blockDim.x + threadIdx.x;
    if (e < E) {
        int d = dst[e];
        int pos = atomicAdd(&h2[d], 1);
        permS[pos] = e;
        srcS[pos] = src[e];
        dstS[pos] = d;
    }
}

// x = mish(node @ Wd^T + bd); write bf16 to xbf (ws) and f32 to agg (d_out)
__global__ void __launch_bounds__(256, 8) node_kernel(const float* __restrict__ nf,
                                                      const ushort* __restrict__ Wd,
                                                      const float* __restrict__ bd,
                                                      ushort* __restrict__ xbf,
                                                      float* __restrict__ agg, int M) {
    __shared__ char lds[TROWS * 512];
    const int base = blockIdx.x * TROWS;
    const int rowsValid = min(TROWS, M - base);
    stage16(nf + (size_t)base * DD, DD, rowsValid, lds);
    __syncthreads();
    f32x4 acc[4];
#pragma unroll
    for (int i = 0; i < 4; ++i) acc[i] = (f32x4){0.f, 0.f, 0.f, 0.f};
    gemm16(lds, Wd, acc);
    const int lane = threadIdx.x & 63;
    const int wave = threadIdx.x >> 6;
    const int colBase = wave * 64;
    const int r = lane & 15, q = lane >> 4;
#pragma unroll
    for (int ct = 0; ct < 4; ++ct) {
        int col = colBase + ct * 16 + r;
        float bb = bd[col];
#pragma unroll
        for (int j = 0; j < 4; ++j) {
            int lrow = q * 4 + j;
            if (lrow < rowsValid) {
                size_t idx = (size_t)(base + lrow) * DD + col;
                float m = mish_f(acc[ct][j] + bb);
                xbf[idx] = (ushort)cvt_pk_bf16(m, m);
                agg[idx] = m;
            }
        }
    }
}

// Sorted-edge kernel, 16-row tile. T14 split: x[src] gather loads ISSUED before the
// GEMM barrier (latency hides under MFMA + Wfrag streaming), parked to LDS after.
// VGPR ~28+12 stays under the 64-reg (256,8) budget -> 8 blocks/CU spill-free.
__global__ void __launch_bounds__(256, 8) edge_kernel(const float* __restrict__ ef,
                                                      const ushort* __restrict__ We,
                                                      const float* __restrict__ be,
                                                      const ushort* __restrict__ xbf,
                                                      const int* __restrict__ permS,
                                                      const int* __restrict__ srcS,
                                                      const int* __restrict__ dstS,
                                                      float* __restrict__ agg, int E) {
    __shared__ char smem[TROWS * BSTRIDE * 2];  // 8448 B: staging (16*512 swz) / xt (16*528)
    __shared__ int permRow[TROWS];
    __shared__ int srcRow[TROWS];
    __shared__ int dstRow[TROWS];

    const int t = threadIdx.x;
    const int base = blockIdx.x * TROWS;
    const int rowsValid = min(TROWS, E - base);

    if (t < TROWS) {
        int gi = base + t;
        int gic = (gi < E) ? gi : (E - 1);
        permRow[t] = permS[gic];
        srcRow[t] = srcS[gic];
        dstRow[t] = (gi < E) ? dstS[gic] : -1;
    }
    __syncthreads();

    // Stage ef rows (16 x 256 fp32 -> bf16 swizzled): 2 iters, cvt_pk + 16B ds_writes.
#pragma unroll
    for (int i = 0; i < 2; ++i) {
        int c = i * 256 + t;
        int row = c >> 5;
        int col8 = (c & 31) << 3;
        float4 va = make_float4(0.f, 0.f, 0.f, 0.f);
        float4 vb = va;
        if (row < rowsValid) {
            const float* p = ef + (size_t)permRow[row] * DD + col8;
            va = *(const float4*)p;
            vb = *(const float4*)(p + 4);
        }
        uint4 h;
        h.x = cvt_pk_bf16(va.x, va.y);
        h.y = cvt_pk_bf16(va.z, va.w);
        h.z = cvt_pk_bf16(vb.x, vb.y);
        h.w = cvt_pk_bf16(vb.z, vb.w);
        int off = row * 512 + ((((c & 31) << 4)) ^ ((row & 7) << 4));
        *(uint4*)(smem + off) = h;
    }

    // T14 issue-early: x[src] gather loads issued BEFORE the GEMM; parked after.
    int4 xv[2];
    int xrow[2], xcol8[2];
#pragma unroll
    for (int i = 0; i < 2; ++i) {
        int c = i * 256 + t;
        xrow[i] = c >> 5;
        xcol8[i] = (c & 31) << 3;
        xv[i] = make_int4(0, 0, 0, 0);
        if (xrow[i] < rowsValid)
            xv[i] = *(const int4*)(xbf + (size_t)srcRow[xrow[i]] * DD + xcol8[i]);
    }
    __syncthreads();   // staging visible

    f32x4 acc[4];
#pragma unroll
    for (int i = 0; i < 4; ++i) acc[i] = (f32x4){0.f, 0.f, 0.f, 0.f};
    gemm16(smem, We, acc);
    __syncthreads();   // staged ef consumed; smem reusable

    // Write-late: park prefetched x rows into LDS.
    ushort* xt = (ushort*)smem;   // [16][BSTRIDE]
#pragma unroll
    for (int i = 0; i < 2; ++i)
        *(int4*)(xt + xrow[i] * BSTRIDE + xcol8[i]) = xv[i];
    __syncthreads();

    // Epilogue: y = mish(acc + be); msg = relu(x + y) written in place over xt.
    const int lane = t & 63;
    const int wave = t >> 6;
    const int colBase = wave * 64;
    const int r = lane & 15, q = lane >> 4;
#pragma unroll
    for (int ct = 0; ct < 4; ++ct) {
        int col = colBase + ct * 16 + r;
        float bb = be[col];
#pragma unroll
        for (int j = 0; j < 4; ++j) {
            int lrow = q * 4 + j;
            float y = mish_f(acc[ct][j] + bb);
            float xval = bf2f(xt[lrow * BSTRIDE + col]);
            float msg = (lrow < rowsValid) ? fmaxf(xval + y, 0.f) : 0.f;
            xt[lrow * BSTRIDE + col] = (ushort)cvt_pk_bf16(msg, msg);
        }
    }
    __syncthreads();

    // Run-reduction: thread t owns col t; dst broadcast -> uniform branches.
    {
        int col = t;
        float run = 0.f;
        int dprev = dstRow[0];
#pragma unroll
        for (int r2 = 0; r2 < TROWS; ++r2) {
            int d = dstRow[r2];
            if (d != dprev) {
                if (dprev >= 0) atomicAdd(agg + (size_t)dprev * DD + col, run);
                run = 0.f;
                dprev = d;
            }
            run += bf2f(xt[r2 * BSTRIDE + col]);
        }
        if (dprev >= 0) atomicAdd(agg + (size_t)dprev * DD + col, run);
    }
}

// out = mish(agg @ Wo^T + bo), in place on agg (= d_out)
__global__ void __launch_bounds__(256, 8) out_kernel(const ushort* __restrict__ Wo,
                                                     const float* __restrict__ bo,
                                                     float* __restrict__ agg_out, int M) {
    __shared__ char lds[TROWS * 512];
    const int base = blockIdx.x * TROWS;
    const int rowsValid = min(TROWS, M - base);
    stage16(agg_out + (size_t)base * DD, DD, rowsValid, lds);
    __syncthreads();
    f32x4 acc[4];
#pragma unroll
    for (int i = 0; i < 4; ++i) acc[i] = (f32x4){0.f, 0.f, 0.f, 0.f};
    gemm16(lds, Wo, acc);
    const int lane = threadIdx.x & 63;
    const int wave = threadIdx.x >> 6;
    const int colBase = wave * 64;
    const int r = lane & 15, q = lane >> 4;
#pragma unroll
    for (int ct = 0; ct < 4; ++ct) {
        int col = colBase + ct * 16 + r;
        float bb = bo[col];
#pragma unroll
        for (int j = 0; j < 4; ++j) {
            int lrow = q * 4 + j;
            if (lrow < rowsValid) {
                size_t idx = (size_t)(base + lrow) * DD + col;
                agg_out[idx] = mish_f(acc[ct][j] + bb);
            }
        }
    }
}

extern "C" void kernel_launch(void* const* d_in, const int* in_sizes, int n_in,
                              void* d_out, int out_size, void* d_ws, size_t ws_size,
                              hipStream_t stream) {
    const float* nf = (const float*)d_in[0];
    const float* ef = (const float*)d_in[1];
    const int* src = (const int*)d_in[3];
    const int* dst = (const int*)d_in[4];
    const float* Wd = (const float*)d_in[5];
    const float* bd = (const float*)d_in[6];
    const float* We = (const float*)d_in[7];
    const float* be = (const float*)d_in[8];
    const float* Wo = (const float*)d_in[9];
    const float* bo = (const float*)d_in[10];

    const int M = in_sizes[0] / DD;   // 20000
    const int E = in_sizes[1] / DD;   // 320000
    float* out = (float*)d_out;       // agg: rst = x + sum(msg)

    auto align = [](size_t v) { return (v + 255) & ~(size_t)255; };
    char* ws = (char*)d_ws;
    size_t off = 0;
    ushort* xbf = (ushort*)(ws + off); off += align((size_t)M * DD * 2);
    ushort* Wdb = (ushort*)(ws + off); off += align((size_t)DD * DD * 2);
    ushort* Web = (ushort*)(ws + off); off += align((size_t)DD * DD * 2);
    ushort* Wob = (ushort*)(ws + off); off += align((size_t)DD * DD * 2);
    int* h     = (int*)(ws + off); off += align((size_t)M * 4);
    int* h2    = (int*)(ws + off); off += align((size_t)M * 4);
    int* bsum  = (int*)(ws + off); off += align(256 * 4);
    int* permS = (int*)(ws + off); off += align((size_t)E * 4);
    int* srcS  = (int*)(ws + off); off += align((size_t)E * 4);
    int* dstS  = (int*)(ws + off); off += align((size_t)E * 4);

    const int nfrag = (DD / 16) * (DD / 32) * 64;  // 8192 fragments per weight
    convert_w_kernel<<<(nfrag + 255) / 256, 256, 0, stream>>>(Wd, Wdb, nfrag);
    convert_w_kernel<<<(nfrag + 255) / 256, 256, 0, stream>>>(We, Web, nfrag);
    convert_w_kernel<<<(nfrag + 255) / 256, 256, 0, stream>>>(Wo, Wob, nfrag);

    // Counting sort by dst (hierarchical scan)
    const int nbScan = (M + 255) / 256;
    zero_kernel<<<(M + 255) / 256, 256, 0, stream>>>(h, M);
    hist_kernel<<<(E + 255) / 256, 256, 0, stream>>>(dst, h, E);
    scan1_kernel<<<nbScan, 256, 0, stream>>>(h, h2, bsum, M);
    scan2_kernel<<<1, 256, 0, stream>>>(bsum, nbScan);
    scan3_kernel<<<nbScan, 256, 0, stream>>>(h2, bsum, M);
    scatter_kernel<<<(E + 255) / 256, 256, 0, stream>>>(src, dst, h2, permS, srcS, dstS, E);

    const int nwgN = (M + TROWS - 1) / TROWS;   // 1250
    node_kernel<<<nwgN, 256, 0, stream>>>(nf, Wdb, bd, xbf, out, M);
    const int nwgE = (E + TROWS - 1) / TROWS;   // 20000
    edge_kernel<<<nwgE, 256, 0, stream>>>(ef, Web, be, xbf, permS, srcS, dstS, out, E);
    out_kernel<<<nwgN, 256, 0, stream>>>(Wob, bo, out, M);
}